// Round 11
// baseline (218.432 us; speedup 1.0000x reference)
//
#include <hip/hip_runtime.h>
#include <math.h>

#define N_NODES 50000
#define M_NB 16
#define K_CAPS 8
#define DD 16
#define D_DIM 128
#define ROUTIT 6

// ---------------------------------------------------------------------------
// Cross-lane / packed-math helpers
// ---------------------------------------------------------------------------
template <int CTRL>
__device__ __forceinline__ float dpp_add(float x) {
    // compiler path (used in fc_norm epilogue only)
    int t = __builtin_amdgcn_update_dpp(0, __float_as_int(x), CTRL, 0xF, 0xF, true);
    return x + __int_as_float(t);
}

__device__ __forceinline__ float xor8_add(float x) {
    // x + x[lane^8] : row_ror:8 within each 16-lane row == xor8, fused DPP add
    float d;
    asm("s_nop 1\n\t"
        "v_add_f32_dpp %0, %1, %1 row_ror:8 row_mask:0xf bank_mask:0xf"
        : "=v"(d) : "v"(x));
    return d;
}

__device__ __forceinline__ float xor16_add(float x) {
#if __has_builtin(__builtin_amdgcn_permlane16_swap)
    unsigned xi = __float_as_uint(x);
    auto r = __builtin_amdgcn_permlane16_swap(xi, xi, false, false);
    return __uint_as_float(r[0]) + __uint_as_float(r[1]);
#else
    return x + __int_as_float(__builtin_amdgcn_ds_swizzle(__float_as_int(x), 0x401F));
#endif
}

__device__ __forceinline__ float xor32_add(float x) {
#if __has_builtin(__builtin_amdgcn_permlane32_swap)
    unsigned xi = __float_as_uint(x);
    auto r = __builtin_amdgcn_permlane32_swap(xi, xi, false, false);
    return __uint_as_float(r[0]) + __uint_as_float(r[1]);
#else
    return x + __shfl_xor(x, 32);
#endif
}

__device__ __forceinline__ float fast_rcp(float x) {
#if __has_builtin(__builtin_amdgcn_rcpf)
    return __builtin_amdgcn_rcpf(x);
#else
    return 1.0f / x;
#endif
}

__device__ __forceinline__ float fast_rsq(float x) {
#if __has_builtin(__builtin_amdgcn_rsqf)
    return __builtin_amdgcn_rsqf(x);
#else
    return 1.0f / sqrtf(x);
#endif
}

__device__ __forceinline__ float fast_exp2(float x) {
#if __has_builtin(__builtin_amdgcn_exp2f)
    return __builtin_amdgcn_exp2f(x);
#else
    return __expf(x * 0.6931471805599453f);   // exp(x*ln2) == 2^x
#endif
}

// Packed 2xFP32 FMA: d = a*b + c componentwise (VOP3P)
__device__ __forceinline__ float2 pk_fma(float2 a, float2 b, float2 c) {
    float2 d;
    asm("v_pk_fma_f32 %0, %1, %2, %3" : "=v"(d) : "v"(a), "v"(b), "v"(c));
    return d;
}

// Fused-DPP butterfly stage over u[8] float2 = 16 floats. s_nop 1 covers the
// VALU-write -> DPP-read hazard at entry.
#define BFLY16(CTRLSTR)                                                        \
    asm ("s_nop 1\n\t"                                                         \
         "v_add_f32_dpp %0, %0, %0 "   CTRLSTR "\n\t"                          \
         "v_add_f32_dpp %1, %1, %1 "   CTRLSTR "\n\t"                          \
         "v_add_f32_dpp %2, %2, %2 "   CTRLSTR "\n\t"                          \
         "v_add_f32_dpp %3, %3, %3 "   CTRLSTR "\n\t"                          \
         "v_add_f32_dpp %4, %4, %4 "   CTRLSTR "\n\t"                          \
         "v_add_f32_dpp %5, %5, %5 "   CTRLSTR "\n\t"                          \
         "v_add_f32_dpp %6, %6, %6 "   CTRLSTR "\n\t"                          \
         "v_add_f32_dpp %7, %7, %7 "   CTRLSTR "\n\t"                          \
         "v_add_f32_dpp %8, %8, %8 "   CTRLSTR "\n\t"                          \
         "v_add_f32_dpp %9, %9, %9 "   CTRLSTR "\n\t"                          \
         "v_add_f32_dpp %10, %10, %10 " CTRLSTR "\n\t"                         \
         "v_add_f32_dpp %11, %11, %11 " CTRLSTR "\n\t"                         \
         "v_add_f32_dpp %12, %12, %12 " CTRLSTR "\n\t"                         \
         "v_add_f32_dpp %13, %13, %13 " CTRLSTR "\n\t"                         \
         "v_add_f32_dpp %14, %14, %14 " CTRLSTR "\n\t"                         \
         "v_add_f32_dpp %15, %15, %15 " CTRLSTR                                \
         : "+v"(u[0].x), "+v"(u[0].y), "+v"(u[1].x), "+v"(u[1].y),             \
           "+v"(u[2].x), "+v"(u[2].y), "+v"(u[3].x), "+v"(u[3].y),             \
           "+v"(u[4].x), "+v"(u[4].y), "+v"(u[5].x), "+v"(u[5].y),             \
           "+v"(u[6].x), "+v"(u[6].y), "+v"(u[7].x), "+v"(u[7].y))

// ---------------------------------------------------------------------------
// K1: per-capsule L2 normalize
// ---------------------------------------------------------------------------
__global__ void normalize_kernel(const float* __restrict__ x,
                                 float* __restrict__ xn) {
    int tid = blockIdx.x * blockDim.x + threadIdx.x;
    if (tid >= N_NODES * K_CAPS) return;
    const float4* p = reinterpret_cast<const float4*>(x + (size_t)tid * DD);
    float4 a0 = p[0], a1 = p[1], a2 = p[2], a3 = p[3];
    float s = a0.x*a0.x + a0.y*a0.y + a0.z*a0.z + a0.w*a0.w
            + a1.x*a1.x + a1.y*a1.y + a1.z*a1.z + a1.w*a1.w
            + a2.x*a2.x + a2.y*a2.y + a2.z*a2.z + a2.w*a2.w
            + a3.x*a3.x + a3.y*a3.y + a3.z*a3.z + a3.w*a3.w;
    float inv = 1.0f / fmaxf(sqrtf(s), 1e-12f);
    float4* q = reinterpret_cast<float4*>(xn + (size_t)tid * DD);
    a0.x *= inv; a0.y *= inv; a0.z *= inv; a0.w *= inv;
    a1.x *= inv; a1.y *= inv; a1.z *= inv; a1.w *= inv;
    a2.x *= inv; a2.y *= inv; a2.z *= inv; a2.w *= inv;
    a3.x *= inv; a3.y *= inv; a3.z *= inv; a3.w *= inv;
    q[0] = a0; q[1] = a1; q[2] = a2; q[3] = a3;
}

// ---------------------------------------------------------------------------
// K2/K4: dynamic routing. One wave per node.
// lane = mh + 8*k : mh = neighbor-half [0,8), k = capsule [0,8)
//
// GATHER (new, r11): the old per-lane gather touched 64 distinct 64B lines per
// load instruction (TA-bound, ~550 line-transactions/wave). Now each load
// instruction fetches 2 FULL contiguous rows (lane = 32*half + 16B-chunk):
// only 16 lines/instruction. Rows staged in wave-private LDS (stride 132
// floats, position swizzle j^=k&3), then each lane reads its (mh,k) slice
// with 8 ds_read_b128. No barriers - wave-coherent, lgkmcnt only.
// Compute loop: pk_fma packed math, DPP butterfly over mh bits {1,2,7},
// deferred norm scale folded into exp2 logits (unchanged from r10).
// ---------------------------------------------------------------------------
__global__ __launch_bounds__(256)
void routing_kernel(const float* __restrict__ xn,
                    const int* __restrict__ nb,
                    float* __restrict__ out) {
    __shared__ float lds[4 * 16 * 132];          // 33792 B: 4 waves x 16 rows x 132
    const int wave = threadIdx.x >> 6;
    const int lane = threadIdx.x & 63;
    const int node = blockIdx.x * 4 + wave;
    const int mh = lane & 7;        // m = mh and mh+8
    const int k  = lane >> 3;       // capsule
    float* wl = &lds[wave * (16 * 132)];

    // neighbor indices in lanes 0..15
    int idxv = 0;
    if (lane < 16) idxv = nb[node * M_NB + lane];

    // coalesced row gather: instruction i fetches rows 2i, 2i+1 contiguously
    const int half = lane >> 5;          // which of the 2 rows
    const int col  = lane & 31;          // 16B chunk within the row
    const int kk = col >> 2;             // capsule of this chunk
    const int jj = col & 3;              // quad within capsule
    const int woff = kk * 16 + (jj ^ (kk & 3)) * 4;   // swizzled slot
#pragma unroll
    for (int i = 0; i < 8; ++i) {
        int r = 2 * i + half;
        int idx = __shfl(idxv, r);
        float4 v = *reinterpret_cast<const float4*>(xn + (size_t)idx * D_DIM + col * 4);
        *reinterpret_cast<float4*>(wl + r * 132 + woff) = v;
    }

    // own row (wave-uniform -> broadcast-coalesced), u/xs init
    const float* xrow = xn + (size_t)node * D_DIM + k * DD;
    float2 u[8], xs[8];
#pragma unroll
    for (int j = 0; j < 4; ++j) {
        float4 v = *reinterpret_cast<const float4*>(xrow + j * 4);
        u[2*j]     = make_float2(v.x, v.y);
        u[2*j + 1] = make_float2(v.z, v.w);
        xs[2*j]     = make_float2(v.x * 0.125f, v.y * 0.125f);  // xn/8 folded
        xs[2*j + 1] = make_float2(v.z * 0.125f, v.w * 0.125f);  // into partials
    }

    // drain LDS writes (wave-coherent; no block barrier needed)
    asm volatile("s_waitcnt lgkmcnt(0)" ::: "memory");

    // read this lane's z slices (un-swizzle: quad j lives at slot j^(k&3))
    float2 z0[8], z1[8];
#pragma unroll
    for (int j = 0; j < 4; ++j) {
        int jsr = j ^ (k & 3);
        float4 a = *reinterpret_cast<const float4*>(wl + mh * 132 + k * 16 + jsr * 4);
        z0[2*j]     = make_float2(a.x, a.y);
        z0[2*j + 1] = make_float2(a.z, a.w);
        float4 b = *reinterpret_cast<const float4*>(wl + (mh + 8) * 132 + k * 16 + jsr * 4);
        z1[2*j]     = make_float2(b.x, b.y);
        z1[2*j + 1] = make_float2(b.z, b.w);
    }

    const float LOG2E = 1.4426950408889634f;
    const float2 zero2 = make_float2(0.f, 0.f);
    float s2 = LOG2E;               // deferred scale * log2(e); exp via exp2

#pragma unroll
    for (int it = 0; it < ROUTIT; ++it) {
        // ---- einsum1: l[m] = (z[m] . u_raw) * s2 ; 2 pk-chains per dot
        float2 a0 = pk_fma(z0[0], u[0], zero2);
        float2 a1 = pk_fma(z0[1], u[1], zero2);
        a0 = pk_fma(z0[2], u[2], a0);
        a1 = pk_fma(z0[3], u[3], a1);
        a0 = pk_fma(z0[4], u[4], a0);
        a1 = pk_fma(z0[5], u[5], a1);
        a0 = pk_fma(z0[6], u[6], a0);
        a1 = pk_fma(z0[7], u[7], a1);
        float2 b0 = pk_fma(z1[0], u[0], zero2);
        float2 b1 = pk_fma(z1[1], u[1], zero2);
        b0 = pk_fma(z1[2], u[2], b0);
        b1 = pk_fma(z1[3], u[3], b1);
        b0 = pk_fma(z1[4], u[4], b0);
        b1 = pk_fma(z1[5], u[5], b1);
        b0 = pk_fma(z1[6], u[6], b0);
        b1 = pk_fma(z1[7], u[7], b1);
        float l0 = (a0.x + a0.y) + (a1.x + a1.y);
        float l1 = (b0.x + b0.y) + (b1.x + b1.y);

        // ---- softmax over k (lane bits 3,4,5): all-VALU reduction
        //      |dot| <= 1 (unit vectors) -> no max subtraction
        float e0 = fast_exp2(l0 * s2);
        float e1 = fast_exp2(l1 * s2);
        float t0 = xor8_add(e0);  float t1 = xor8_add(e1);
        t0 = xor16_add(t0);       t1 = xor16_add(t1);
        t0 = xor32_add(t0);       t1 = xor32_add(t1);
        float p0 = e0 * fast_rcp(t0);
        float p1 = e1 * fast_rcp(t1);

        // ---- einsum2 lane-partial: z0*p0 + z1*p1 + xn/8 (packed)
        float2 p0b = make_float2(p0, p0);
        float2 p1b = make_float2(p1, p1);
#pragma unroll
        for (int j = 0; j < 8; ++j)
            u[j] = pk_fma(z1[j], p1b, pk_fma(z0[j], p0b, xs[j]));

        // ---- m-reduce over mh bits[2:0]: pure fused-DPP butterfly
        // {1,2,7} is a GF(2)^3 basis -> full all-reduce over 8 contiguous lanes
        BFLY16("quad_perm:[1,0,3,2] row_mask:0xf bank_mask:0xf");  // xor 1
        BFLY16("quad_perm:[2,3,0,1] row_mask:0xf bank_mask:0xf");  // xor 2
        BFLY16("row_half_mirror row_mask:0xf bank_mask:0xf");      // xor 7

        // ---- deferred renorm: scale only (all but last iteration), packed
        if (it < ROUTIT - 1) {
            float2 q0 = pk_fma(u[0], u[0], zero2);
            float2 q1 = pk_fma(u[1], u[1], zero2);
            q0 = pk_fma(u[2], u[2], q0);
            q1 = pk_fma(u[3], u[3], q1);
            q0 = pk_fma(u[4], u[4], q0);
            q1 = pk_fma(u[5], u[5], q1);
            q0 = pk_fma(u[6], u[6], q0);
            q1 = pk_fma(u[7], u[7], q1);
            float nrm = (q0.x + q0.y) + (q1.x + q1.y);
            s2 = fast_rsq(fmaxf(nrm, 1e-24f)) * LOG2E;
        }
    }

    // ---- output: relu(u_raw). u identical across the 8 mh-lanes of each
    // k group; lane mh==j (j<4) stores quad j (pairs 2j,2j+1) of cap k.
#pragma unroll
    for (int j = 0; j < 8; ++j) {
        u[j].x = fmaxf(u[j].x, 0.f);
        u[j].y = fmaxf(u[j].y, 0.f);
    }
#pragma unroll
    for (int j = 0; j < 4; ++j) {
        if (mh == j) {
            float4 v = make_float4(u[2*j].x, u[2*j].y, u[2*j+1].x, u[2*j+1].y);
            *reinterpret_cast<float4*>(out + (size_t)node * D_DIM + k * DD + j * 4) = v;
        }
    }
}

// ---------------------------------------------------------------------------
// K3: xn1 = normalize_per_capsule( relu( h0 @ W^T + b ) )  (unchanged, ~16us)
// Wt4[k4*129 + col]: conflict-free by construction (consecutive float4 reads)
// ---------------------------------------------------------------------------
__global__ __launch_bounds__(256, 2)
void fc_norm_kernel(const float* __restrict__ h,
                    const float* __restrict__ W,
                    const float* __restrict__ b,
                    float* __restrict__ xnout) {
    __shared__ float4 Wt4[32 * 129];     // 66048 B
    __shared__ float4 hrow4[8 * 32];     // 4096 B

    const float4* W4 = reinterpret_cast<const float4*>(W);
    for (int t = threadIdx.x; t < 128 * 32; t += 256) {
        Wt4[(t & 31) * 129 + (t >> 5)] = W4[t];
    }
    __syncthreads();

    const int col = threadIdx.x & 127;
    const int rr  = threadIdx.x >> 7;          // 0 -> rows 0..3, 1 -> rows 4..7
    const float bias = b[col];

    for (int row0 = blockIdx.x * 8; row0 < N_NODES; row0 += gridDim.x * 8) {
        __syncthreads();
        {
            int t = threadIdx.x;
            hrow4[t] = *reinterpret_cast<const float4*>(
                h + (size_t)(row0 + (t >> 5)) * D_DIM + (t & 31) * 4);
        }
        __syncthreads();

        float acc0 = bias, acc1 = bias, acc2 = bias, acc3 = bias;
#pragma unroll
        for (int k4 = 0; k4 < 32; ++k4) {
            float4 w4 = Wt4[k4 * 129 + col];
            float4 h0 = hrow4[(rr * 4 + 0) * 32 + k4];
            float4 h1 = hrow4[(rr * 4 + 1) * 32 + k4];
            float4 h2 = hrow4[(rr * 4 + 2) * 32 + k4];
            float4 h3 = hrow4[(rr * 4 + 3) * 32 + k4];
            acc0 = fmaf(w4.x, h0.x, acc0); acc0 = fmaf(w4.y, h0.y, acc0);
            acc0 = fmaf(w4.z, h0.z, acc0); acc0 = fmaf(w4.w, h0.w, acc0);
            acc1 = fmaf(w4.x, h1.x, acc1); acc1 = fmaf(w4.y, h1.y, acc1);
            acc1 = fmaf(w4.z, h1.z, acc1); acc1 = fmaf(w4.w, h1.w, acc1);
            acc2 = fmaf(w4.x, h2.x, acc2); acc2 = fmaf(w4.y, h2.y, acc2);
            acc2 = fmaf(w4.z, h2.z, acc2); acc2 = fmaf(w4.w, h2.w, acc2);
            acc3 = fmaf(w4.x, h3.x, acc3); acc3 = fmaf(w4.y, h3.y, acc3);
            acc3 = fmaf(w4.z, h3.z, acc3); acc3 = fmaf(w4.w, h3.w, acc3);
        }

        float a[4] = {fmaxf(acc0, 0.f), fmaxf(acc1, 0.f),
                      fmaxf(acc2, 0.f), fmaxf(acc3, 0.f)};
#pragma unroll
        for (int j = 0; j < 4; ++j) {
            float s = a[j] * a[j];
            s = dpp_add<0xB1>(s);
            s = dpp_add<0x4E>(s);
            s = dpp_add<0x141>(s);
            s = dpp_add<0x140>(s);
            float inv = fast_rsq(fmaxf(s, 1e-24f));
            xnout[(size_t)(row0 + rr * 4 + j) * D_DIM + col] = a[j] * inv;
        }
    }
}

// ---------------------------------------------------------------------------
extern "C" void kernel_launch(void* const* d_in, const int* in_sizes, int n_in,
                              void* d_out, int out_size, void* d_ws, size_t ws_size,
                              hipStream_t stream) {
    const float* x  = (const float*)d_in[0];
    const int*   nb = (const int*)d_in[1];
    const float* W  = (const float*)d_in[2];
    const float* bb = (const float*)d_in[3];
    float* out = (float*)d_out;

    float* xnbuf = (float*)d_ws;                          // 25.6 MB
    float* h0    = xnbuf + (size_t)N_NODES * D_DIM;       // 25.6 MB

    // layer 0
    normalize_kernel<<<(N_NODES * K_CAPS + 255) / 256, 256, 0, stream>>>(x, xnbuf);
    routing_kernel<<<N_NODES / 4, 256, 0, stream>>>(xnbuf, nb, h0);
    // layer 1  (50000 % 8 == 0 -> no row tail)
    fc_norm_kernel<<<1024, 256, 0, stream>>>(h0, W, bb, xnbuf);
    routing_kernel<<<N_NODES / 4, 256, 0, stream>>>(xnbuf, nb, out);
}

// Round 12
// 205.143 us; speedup vs baseline: 1.0648x; 1.0648x over previous
//
#include <hip/hip_runtime.h>
#include <math.h>

#define N_NODES 50000
#define M_NB 16
#define K_CAPS 8
#define DD 16
#define D_DIM 128
#define ROUTIT 6

// ---------------------------------------------------------------------------
// Cross-lane / packed-math helpers
// ---------------------------------------------------------------------------
template <int CTRL>
__device__ __forceinline__ float dpp_add(float x) {
    int t = __builtin_amdgcn_update_dpp(0, __float_as_int(x), CTRL, 0xF, 0xF, true);
    return x + __int_as_float(t);
}

__device__ __forceinline__ float xor8_add(float x) {
    float d;
    asm("s_nop 1\n\t"
        "v_add_f32_dpp %0, %1, %1 row_ror:8 row_mask:0xf bank_mask:0xf"
        : "=v"(d) : "v"(x));
    return d;
}

__device__ __forceinline__ float xor16_add(float x) {
#if __has_builtin(__builtin_amdgcn_permlane16_swap)
    unsigned xi = __float_as_uint(x);
    auto r = __builtin_amdgcn_permlane16_swap(xi, xi, false, false);
    return __uint_as_float(r[0]) + __uint_as_float(r[1]);
#else
    return x + __int_as_float(__builtin_amdgcn_ds_swizzle(__float_as_int(x), 0x401F));
#endif
}

__device__ __forceinline__ float xor32_add(float x) {
#if __has_builtin(__builtin_amdgcn_permlane32_swap)
    unsigned xi = __float_as_uint(x);
    auto r = __builtin_amdgcn_permlane32_swap(xi, xi, false, false);
    return __uint_as_float(r[0]) + __uint_as_float(r[1]);
#else
    return x + __shfl_xor(x, 32);
#endif
}

__device__ __forceinline__ float fast_rcp(float x) {
#if __has_builtin(__builtin_amdgcn_rcpf)
    return __builtin_amdgcn_rcpf(x);
#else
    return 1.0f / x;
#endif
}

__device__ __forceinline__ float fast_rsq(float x) {
#if __has_builtin(__builtin_amdgcn_rsqf)
    return __builtin_amdgcn_rsqf(x);
#else
    return 1.0f / sqrtf(x);
#endif
}

__device__ __forceinline__ float fast_exp2(float x) {
#if __has_builtin(__builtin_amdgcn_exp2f)
    return __builtin_amdgcn_exp2f(x);
#else
    return __expf(x * 0.6931471805599453f);
#endif
}

// Packed 2xFP32 FMA (VOP3P)
__device__ __forceinline__ float2 pk_fma(float2 a, float2 b, float2 c) {
    float2 d;
    asm("v_pk_fma_f32 %0, %1, %2, %3" : "=v"(d) : "v"(a), "v"(b), "v"(c));
    return d;
}

// bf16 pair (packed in one u32, little-endian: lo16 = elem 2j, hi16 = 2j+1)
// -> float2, exact (bf16 is f32 with truncated mantissa)
__device__ __forceinline__ float2 bf2(unsigned w) {
    return make_float2(__uint_as_float(w << 16),
                       __uint_as_float(w & 0xFFFF0000u));
}

// 2x f32 -> packed bf16 u32, RNE (gfx950 v_cvt_pk_bf16_f32)
__device__ __forceinline__ unsigned cvt_pk_bf16(float lo, float hi) {
    unsigned r;
    asm("v_cvt_pk_bf16_f32 %0, %1, %2" : "=v"(r) : "v"(lo), "v"(hi));
    return r;
}

// scalar f32 -> bf16 (RNE)
__device__ __forceinline__ unsigned short f2bf(float v) {
    unsigned u = __float_as_uint(v);
    u = (u + 0x7FFFu + ((u >> 16) & 1u)) >> 16;
    return (unsigned short)u;
}

// Fused-DPP butterfly stage over u[8] float2 = 16 floats.
#define BFLY16(CTRLSTR)                                                        \
    asm ("s_nop 1\n\t"                                                         \
         "v_add_f32_dpp %0, %0, %0 "   CTRLSTR "\n\t"                          \
         "v_add_f32_dpp %1, %1, %1 "   CTRLSTR "\n\t"                          \
         "v_add_f32_dpp %2, %2, %2 "   CTRLSTR "\n\t"                          \
         "v_add_f32_dpp %3, %3, %3 "   CTRLSTR "\n\t"                          \
         "v_add_f32_dpp %4, %4, %4 "   CTRLSTR "\n\t"                          \
         "v_add_f32_dpp %5, %5, %5 "   CTRLSTR "\n\t"                          \
         "v_add_f32_dpp %6, %6, %6 "   CTRLSTR "\n\t"                          \
         "v_add_f32_dpp %7, %7, %7 "   CTRLSTR "\n\t"                          \
         "v_add_f32_dpp %8, %8, %8 "   CTRLSTR "\n\t"                          \
         "v_add_f32_dpp %9, %9, %9 "   CTRLSTR "\n\t"                          \
         "v_add_f32_dpp %10, %10, %10 " CTRLSTR "\n\t"                         \
         "v_add_f32_dpp %11, %11, %11 " CTRLSTR "\n\t"                         \
         "v_add_f32_dpp %12, %12, %12 " CTRLSTR "\n\t"                         \
         "v_add_f32_dpp %13, %13, %13 " CTRLSTR "\n\t"                         \
         "v_add_f32_dpp %14, %14, %14 " CTRLSTR "\n\t"                         \
         "v_add_f32_dpp %15, %15, %15 " CTRLSTR                                \
         : "+v"(u[0].x), "+v"(u[0].y), "+v"(u[1].x), "+v"(u[1].y),             \
           "+v"(u[2].x), "+v"(u[2].y), "+v"(u[3].x), "+v"(u[3].y),             \
           "+v"(u[4].x), "+v"(u[4].y), "+v"(u[5].x), "+v"(u[5].y),             \
           "+v"(u[6].x), "+v"(u[6].y), "+v"(u[7].x), "+v"(u[7].y))

// ---------------------------------------------------------------------------
// K1: per-capsule L2 normalize -> bf16 table (RNE). One thread per capsule.
// ---------------------------------------------------------------------------
__global__ void normalize_kernel(const float* __restrict__ x,
                                 unsigned short* __restrict__ xnb) {
    int tid = blockIdx.x * blockDim.x + threadIdx.x;
    if (tid >= N_NODES * K_CAPS) return;
    const float4* p = reinterpret_cast<const float4*>(x + (size_t)tid * DD);
    float4 a0 = p[0], a1 = p[1], a2 = p[2], a3 = p[3];
    float s = a0.x*a0.x + a0.y*a0.y + a0.z*a0.z + a0.w*a0.w
            + a1.x*a1.x + a1.y*a1.y + a1.z*a1.z + a1.w*a1.w
            + a2.x*a2.x + a2.y*a2.y + a2.z*a2.z + a2.w*a2.w
            + a3.x*a3.x + a3.y*a3.y + a3.z*a3.z + a3.w*a3.w;
    float inv = 1.0f / fmaxf(sqrtf(s), 1e-12f);
    a0.x *= inv; a0.y *= inv; a0.z *= inv; a0.w *= inv;
    a1.x *= inv; a1.y *= inv; a1.z *= inv; a1.w *= inv;
    a2.x *= inv; a2.y *= inv; a2.z *= inv; a2.w *= inv;
    a3.x *= inv; a3.y *= inv; a3.z *= inv; a3.w *= inv;
    uint4 w0, w1;
    w0.x = cvt_pk_bf16(a0.x, a0.y); w0.y = cvt_pk_bf16(a0.z, a0.w);
    w0.z = cvt_pk_bf16(a1.x, a1.y); w0.w = cvt_pk_bf16(a1.z, a1.w);
    w1.x = cvt_pk_bf16(a2.x, a2.y); w1.y = cvt_pk_bf16(a2.z, a2.w);
    w1.z = cvt_pk_bf16(a3.x, a3.y); w1.w = cvt_pk_bf16(a3.z, a3.w);
    uint4* q = reinterpret_cast<uint4*>(xnb + (size_t)tid * DD);
    q[0] = w0; q[1] = w1;
}

// ---------------------------------------------------------------------------
// K2/K4: dynamic routing. One wave per node.
// lane = mh + 8*k : mh = neighbor-half [0,8), k = capsule [0,8)
// Gather table is bf16 (256 B/row): halves L2-miss traffic AND table is
// 12.8 MB vs 4 MB/XCD L2 -> higher hit rate (r11 diagnosis: routing is
// outstanding-miss bound, time = misses x latency / queue-depth).
// Compute in f32: pk_fma packed math, DPP butterfly over mh bits {1,2,7},
// deferred norm scale folded into exp2 logits.
// ---------------------------------------------------------------------------
__global__ __launch_bounds__(256)
void routing_kernel(const unsigned short* __restrict__ xnb,
                    const int* __restrict__ nb,
                    float* __restrict__ out) {
    const int wave = threadIdx.x >> 6;
    const int lane = threadIdx.x & 63;
    const int node = blockIdx.x * 4 + wave;
    const int mh = lane & 7;        // m = mh and mh+8
    const int k  = lane >> 3;       // capsule

    const int idx0 = nb[node * M_NB + mh];
    const int idx1 = nb[node * M_NB + mh + 8];
    const uint4* zp0 = reinterpret_cast<const uint4*>(xnb + (size_t)idx0 * D_DIM + k * DD);
    const uint4* zp1 = reinterpret_cast<const uint4*>(xnb + (size_t)idx1 * D_DIM + k * DD);
    uint4 A0 = zp0[0], A1 = zp0[1];
    uint4 B0 = zp1[0], B1 = zp1[1];

    // own row (broadcast-coalesced across the 8 mh-lanes of each k)
    const uint4* xp = reinterpret_cast<const uint4*>(xnb + (size_t)node * D_DIM + k * DD);
    uint4 X0 = xp[0], X1 = xp[1];

    float2 z0[8], z1[8], u[8], xs[8];
    z0[0] = bf2(A0.x); z0[1] = bf2(A0.y); z0[2] = bf2(A0.z); z0[3] = bf2(A0.w);
    z0[4] = bf2(A1.x); z0[5] = bf2(A1.y); z0[6] = bf2(A1.z); z0[7] = bf2(A1.w);
    z1[0] = bf2(B0.x); z1[1] = bf2(B0.y); z1[2] = bf2(B0.z); z1[3] = bf2(B0.w);
    z1[4] = bf2(B1.x); z1[5] = bf2(B1.y); z1[6] = bf2(B1.z); z1[7] = bf2(B1.w);
    u[0] = bf2(X0.x); u[1] = bf2(X0.y); u[2] = bf2(X0.z); u[3] = bf2(X0.w);
    u[4] = bf2(X1.x); u[5] = bf2(X1.y); u[6] = bf2(X1.z); u[7] = bf2(X1.w);
#pragma unroll
    for (int j = 0; j < 8; ++j)
        xs[j] = make_float2(u[j].x * 0.125f, u[j].y * 0.125f);  // xn/8 folded

    const float LOG2E = 1.4426950408889634f;
    const float2 zero2 = make_float2(0.f, 0.f);
    float s2 = LOG2E;               // deferred scale * log2(e); exp via exp2

#pragma unroll
    for (int it = 0; it < ROUTIT; ++it) {
        // ---- einsum1: l[m] = (z[m] . u_raw) * s2 ; 2 pk-chains per dot
        float2 a0 = pk_fma(z0[0], u[0], zero2);
        float2 a1 = pk_fma(z0[1], u[1], zero2);
        a0 = pk_fma(z0[2], u[2], a0);
        a1 = pk_fma(z0[3], u[3], a1);
        a0 = pk_fma(z0[4], u[4], a0);
        a1 = pk_fma(z0[5], u[5], a1);
        a0 = pk_fma(z0[6], u[6], a0);
        a1 = pk_fma(z0[7], u[7], a1);
        float2 b0 = pk_fma(z1[0], u[0], zero2);
        float2 b1 = pk_fma(z1[1], u[1], zero2);
        b0 = pk_fma(z1[2], u[2], b0);
        b1 = pk_fma(z1[3], u[3], b1);
        b0 = pk_fma(z1[4], u[4], b0);
        b1 = pk_fma(z1[5], u[5], b1);
        b0 = pk_fma(z1[6], u[6], b0);
        b1 = pk_fma(z1[7], u[7], b1);
        float l0 = (a0.x + a0.y) + (a1.x + a1.y);
        float l1 = (b0.x + b0.y) + (b1.x + b1.y);

        // ---- softmax over k (lane bits 3,4,5): all-VALU reduction
        float e0 = fast_exp2(l0 * s2);
        float e1 = fast_exp2(l1 * s2);
        float t0 = xor8_add(e0);  float t1 = xor8_add(e1);
        t0 = xor16_add(t0);       t1 = xor16_add(t1);
        t0 = xor32_add(t0);       t1 = xor32_add(t1);
        float p0 = e0 * fast_rcp(t0);
        float p1 = e1 * fast_rcp(t1);

        // ---- einsum2 lane-partial: z0*p0 + z1*p1 + xn/8 (packed)
        float2 p0b = make_float2(p0, p0);
        float2 p1b = make_float2(p1, p1);
#pragma unroll
        for (int j = 0; j < 8; ++j)
            u[j] = pk_fma(z1[j], p1b, pk_fma(z0[j], p0b, xs[j]));

        // ---- m-reduce over mh bits[2:0]: pure fused-DPP butterfly
        BFLY16("quad_perm:[1,0,3,2] row_mask:0xf bank_mask:0xf");  // xor 1
        BFLY16("quad_perm:[2,3,0,1] row_mask:0xf bank_mask:0xf");  // xor 2
        BFLY16("row_half_mirror row_mask:0xf bank_mask:0xf");      // xor 7

        // ---- deferred renorm: scale only (all but last iteration), packed
        if (it < ROUTIT - 1) {
            float2 q0 = pk_fma(u[0], u[0], zero2);
            float2 q1 = pk_fma(u[1], u[1], zero2);
            q0 = pk_fma(u[2], u[2], q0);
            q1 = pk_fma(u[3], u[3], q1);
            q0 = pk_fma(u[4], u[4], q0);
            q1 = pk_fma(u[5], u[5], q1);
            q0 = pk_fma(u[6], u[6], q0);
            q1 = pk_fma(u[7], u[7], q1);
            float nrm = (q0.x + q0.y) + (q1.x + q1.y);
            s2 = fast_rsq(fmaxf(nrm, 1e-24f)) * LOG2E;
        }
    }

    // ---- output: relu(u_raw), f32. lane mh==j (j<4) stores quad j of cap k.
#pragma unroll
    for (int j = 0; j < 8; ++j) {
        u[j].x = fmaxf(u[j].x, 0.f);
        u[j].y = fmaxf(u[j].y, 0.f);
    }
#pragma unroll
    for (int j = 0; j < 4; ++j) {
        if (mh == j) {
            float4 v = make_float4(u[2*j].x, u[2*j].y, u[2*j+1].x, u[2*j+1].y);
            *reinterpret_cast<float4*>(out + (size_t)node * D_DIM + k * DD + j * 4) = v;
        }
    }
}

// ---------------------------------------------------------------------------
// K3: xnb1 = bf16( normalize_per_capsule( relu( h0 @ W^T + b ) ) )
// GEMM in f32 (conflict-free Wt4 layout), epilogue writes bf16 (RNE).
// ---------------------------------------------------------------------------
__global__ __launch_bounds__(256, 2)
void fc_norm_kernel(const float* __restrict__ h,
                    const float* __restrict__ W,
                    const float* __restrict__ b,
                    unsigned short* __restrict__ xnbout) {
    __shared__ float4 Wt4[32 * 129];     // 66048 B
    __shared__ float4 hrow4[8 * 32];     // 4096 B

    const float4* W4 = reinterpret_cast<const float4*>(W);
    for (int t = threadIdx.x; t < 128 * 32; t += 256) {
        Wt4[(t & 31) * 129 + (t >> 5)] = W4[t];
    }
    __syncthreads();

    const int col = threadIdx.x & 127;
    const int rr  = threadIdx.x >> 7;          // 0 -> rows 0..3, 1 -> rows 4..7
    const float bias = b[col];

    for (int row0 = blockIdx.x * 8; row0 < N_NODES; row0 += gridDim.x * 8) {
        __syncthreads();
        {
            int t = threadIdx.x;
            hrow4[t] = *reinterpret_cast<const float4*>(
                h + (size_t)(row0 + (t >> 5)) * D_DIM + (t & 31) * 4);
        }
        __syncthreads();

        float acc0 = bias, acc1 = bias, acc2 = bias, acc3 = bias;
#pragma unroll
        for (int k4 = 0; k4 < 32; ++k4) {
            float4 w4 = Wt4[k4 * 129 + col];
            float4 h0 = hrow4[(rr * 4 + 0) * 32 + k4];
            float4 h1 = hrow4[(rr * 4 + 1) * 32 + k4];
            float4 h2 = hrow4[(rr * 4 + 2) * 32 + k4];
            float4 h3 = hrow4[(rr * 4 + 3) * 32 + k4];
            acc0 = fmaf(w4.x, h0.x, acc0); acc0 = fmaf(w4.y, h0.y, acc0);
            acc0 = fmaf(w4.z, h0.z, acc0); acc0 = fmaf(w4.w, h0.w, acc0);
            acc1 = fmaf(w4.x, h1.x, acc1); acc1 = fmaf(w4.y, h1.y, acc1);
            acc1 = fmaf(w4.z, h1.z, acc1); acc1 = fmaf(w4.w, h1.w, acc1);
            acc2 = fmaf(w4.x, h2.x, acc2); acc2 = fmaf(w4.y, h2.y, acc2);
            acc2 = fmaf(w4.z, h2.z, acc2); acc2 = fmaf(w4.w, h2.w, acc2);
            acc3 = fmaf(w4.x, h3.x, acc3); acc3 = fmaf(w4.y, h3.y, acc3);
            acc3 = fmaf(w4.z, h3.z, acc3); acc3 = fmaf(w4.w, h3.w, acc3);
        }

        float a[4] = {fmaxf(acc0, 0.f), fmaxf(acc1, 0.f),
                      fmaxf(acc2, 0.f), fmaxf(acc3, 0.f)};
#pragma unroll
        for (int j = 0; j < 4; ++j) {
            float s = a[j] * a[j];
            s = dpp_add<0xB1>(s);
            s = dpp_add<0x4E>(s);
            s = dpp_add<0x141>(s);
            s = dpp_add<0x140>(s);
            float inv = fast_rsq(fmaxf(s, 1e-24f));
            xnbout[(size_t)(row0 + rr * 4 + j) * D_DIM + col] = f2bf(a[j] * inv);
        }
    }
}

// ---------------------------------------------------------------------------
extern "C" void kernel_launch(void* const* d_in, const int* in_sizes, int n_in,
                              void* d_out, int out_size, void* d_ws, size_t ws_size,
                              hipStream_t stream) {
    const float* x  = (const float*)d_in[0];
    const int*   nb = (const int*)d_in[1];
    const float* W  = (const float*)d_in[2];
    const float* bb = (const float*)d_in[3];
    float* out = (float*)d_out;

    unsigned short* xnb = (unsigned short*)d_ws;          // 12.8 MB bf16 table
    float* h0 = (float*)((char*)d_ws + (size_t)N_NODES * D_DIM * 2);  // 25.6 MB

    // layer 0
    normalize_kernel<<<(N_NODES * K_CAPS + 255) / 256, 256, 0, stream>>>(x, xnb);
    routing_kernel<<<N_NODES / 4, 256, 0, stream>>>(xnb, nb, h0);
    // layer 1 (fc overwrites xnb in place; layer-0 routing is complete)
    fc_norm_kernel<<<1024, 256, 0, stream>>>(h0, W, bb, xnb);
    routing_kernel<<<N_NODES / 4, 256, 0, stream>>>(xnb, nb, out);
}